// Round 7
// baseline (654.966 us; speedup 1.0000x reference)
//
#include <hip/hip_runtime.h>

#define D 128
#define NB 512   // bucket slots per domain (bucket = node >> 8)

typedef __attribute__((ext_vector_type(8))) short bf16x8;
typedef __attribute__((ext_vector_type(4))) float f32x4;
typedef __attribute__((ext_vector_type(2))) float f32x2;

static __device__ inline unsigned pack_bf16x2(float a, float b) {
    unsigned ua = __float_as_uint(a);
    unsigned ub = __float_as_uint(b);
    ua += 0x7fffu + ((ua >> 16) & 1u);
    ub += 0x7fffu + ((ub >> 16) & 1u);
    return (ua >> 16) | (ub & 0xffff0000u);
}

// ---- bucket histogram + global node histogram (both domains via blockIdx.y) ----
__global__ __launch_bounds__(256) void bhist_k(const int* __restrict__ dst_s,
                                               const int* __restrict__ dst_t,
                                               int* __restrict__ bcnt,
                                               int* __restrict__ ncnt, int E, int N) {
    int d = blockIdx.y;
    const int* dst = d ? dst_t : dst_s;
    int* nc = ncnt + (size_t)d * (N + 1);
    __shared__ int h[NB];
    for (int i = threadIdx.x; i < NB; i += 256) h[i] = 0;
    __syncthreads();
    int stride = gridDim.x * 256;
    for (int e = blockIdx.x * 256 + threadIdx.x; e < E; e += stride) {
        int dd = dst[e];
        atomicAdd(&h[dd >> 8], 1);
        atomicAdd(&nc[dd], 1);
    }
    __syncthreads();
    for (int i = threadIdx.x; i < NB; i += 256)
        if (h[i]) atomicAdd(&bcnt[d * NB + i], h[i]);
}

// ---- exclusive scan of 1024 bucket counts (both domains, one block) ----
__global__ __launch_bounds__(1024) void scanB_k(const int* __restrict__ bcnt,
                                                int* __restrict__ bbase,
                                                int* __restrict__ cursor) {
    __shared__ int sh[1024];
    int t = threadIdx.x;
    int v = bcnt[t];
    sh[t] = v;
    __syncthreads();
    for (int o = 1; o < 1024; o <<= 1) {
        int x = (t >= o) ? sh[t - o] : 0;
        __syncthreads();
        sh[t] += x;
        __syncthreads();
    }
    int ex = sh[t] - v;
    bbase[t] = ex; cursor[t] = ex;
    if (t == 1023) bbase[1024] = sh[1023];
}

// ---- dinv + padded degree (units of list slots, multiple of 8) ----
__global__ __launch_bounds__(256) void deg_k(const int* __restrict__ ncnt,
                                             float* __restrict__ dinv,
                                             int* __restrict__ pval, int N) {
    int d = blockIdx.y;
    int i = blockIdx.x * 256 + threadIdx.x;
    if (i > N) return;
    size_t ix = (size_t)d * (N + 1) + i;
    if (i == N) { dinv[ix] = 0.f; pval[ix] = 0; }
    else {
        int c = ncnt[ix];
        dinv[ix] = rsqrtf((float)(c + 1));
        pval[ix] = ((c + 1 + 7) >> 3) << 3;   // deg + self, padded to 8
    }
}

// ---- 3-pass exclusive scan over M = 2*(N+1) padded degrees -> offs_pad ----
__global__ __launch_bounds__(256) void scan_bsum_k(const int* __restrict__ cnt,
                                                   int* __restrict__ bsum, int n) {
    __shared__ int sh[256];
    int tid = threadIdx.x;
    int base = blockIdx.x * 1024 + tid * 4;
    int local = 0;
    #pragma unroll
    for (int j = 0; j < 4; ++j) if (base + j < n) local += cnt[base + j];
    sh[tid] = local;
    __syncthreads();
    for (int o = 128; o > 0; o >>= 1) {
        if (tid < o) sh[tid] += sh[tid + o];
        __syncthreads();
    }
    if (tid == 0) bsum[blockIdx.x] = sh[0];
}

__global__ void scan_serial_k(int* __restrict__ bsum, int nb) {
    if (threadIdx.x == 0 && blockIdx.x == 0) {
        int run = 0;
        for (int i = 0; i < nb; ++i) { int v = bsum[i]; bsum[i] = run; run += v; }
    }
}

__global__ __launch_bounds__(256) void scan_final_k(const int* __restrict__ cnt,
                                                    const int* __restrict__ bofs,
                                                    int* __restrict__ offs, int n) {
    __shared__ int sh[256];
    int tid = threadIdx.x;
    int base = blockIdx.x * 1024 + tid * 4;
    int v[4];
    int local = 0;
    #pragma unroll
    for (int j = 0; j < 4; ++j) {
        v[j] = (base + j < n) ? cnt[base + j] : 0;
        local += v[j];
    }
    sh[tid] = local;
    __syncthreads();
    for (int o = 1; o < 256; o <<= 1) {
        int t = (tid >= o) ? sh[tid - o] : 0;
        __syncthreads();
        sh[tid] += t;
        __syncthreads();
    }
    int run = sh[tid] - local + bofs[blockIdx.x];
    #pragma unroll
    for (int j = 0; j < 4; ++j) {
        if (base + j < n) { offs[base + j] = run; run += v[j]; }
    }
}

// ---- bin edges into bucket regions: src | (dst&255)<<24 ----
__global__ __launch_bounds__(256) void bin_k(const int* __restrict__ src_s,
                                             const int* __restrict__ dst_s,
                                             const int* __restrict__ src_t,
                                             const int* __restrict__ dst_t,
                                             int* __restrict__ cursor,
                                             unsigned* __restrict__ pairs, int E) {
    int d = blockIdx.y;
    const int* src = d ? src_t : src_s;
    const int* dst = d ? dst_t : dst_s;
    int* cur = cursor + d * NB;
    __shared__ int h[NB];
    __shared__ int gb[NB];
    int t0 = blockIdx.x * 2048;
    if (t0 >= E) return;
    for (int i = threadIdx.x; i < NB; i += 256) h[i] = 0;
    __syncthreads();
    int rank[8]; unsigned pk[8]; short bk[8];
    #pragma unroll
    for (int j = 0; j < 8; ++j) {
        int e = t0 + j * 256 + threadIdx.x;
        if (e < E) {
            int dd = dst[e], s = src[e];
            bk[j] = (short)(dd >> 8);
            pk[j] = (unsigned)s | ((unsigned)(dd & 255) << 24);
            rank[j] = atomicAdd(&h[dd >> 8], 1);
        } else bk[j] = -1;
    }
    __syncthreads();
    for (int i = threadIdx.x; i < NB; i += 256)
        gb[i] = h[i] ? atomicAdd(&cur[i], h[i]) : 0;
    __syncthreads();
    #pragma unroll
    for (int j = 0; j < 8; ++j)
        if (bk[j] >= 0) pairs[gb[bk[j]] + rank[j]] = pk[j];
}

// ---- per-bucket scatter into padded CSR + self/sentinel fill ----
__global__ __launch_bounds__(256) void csrb_k(const unsigned* __restrict__ pairs,
                                              const int* __restrict__ bbase,
                                              const int* __restrict__ offs,
                                              int* __restrict__ csr, int N) {
    int d = blockIdx.y, bx = blockIdx.x, t = threadIdx.x;
    int g = d * NB + bx;
    int e0 = bbase[g], e1 = bbase[g + 1];
    const int* of = offs + (size_t)d * (N + 1) + (bx << 8);
    __shared__ int lc[256];
    lc[t] = 0;
    __syncthreads();
    for (int e = e0 + t; e < e1; e += 256) {
        unsigned p = pairs[e];
        int dn = p >> 24;
        int rank = atomicAdd(&lc[dn], 1);
        csr[of[dn] + rank] = (int)(p & 0xffffffu);
    }
    __syncthreads();
    int node = (bx << 8) + t;
    if (node < N) {
        int base = of[t], end = of[t + 1];
        int deg = lc[t];
        csr[base + deg] = node;                          // self (pre-scaled row IS the self term)
        for (int k = deg + 1; k < end - base; ++k) csr[base + k] = N;   // sentinel zero-row
    }
}

// ================= MFMA GEMM =================
__global__ __launch_bounds__(256) void packW_k(const float* __restrict__ W1,
                                               const float* __restrict__ W2,
                                               unsigned short* __restrict__ wp1,
                                               unsigned short* __restrict__ wp2) {
    const float* W = blockIdx.x ? W2 : W1;
    unsigned short* wp = blockIdx.x ? wp2 : wp1;
    for (int idx = threadIdx.x; idx < 2048; idx += 256) {
        int f = idx >> 6, lane = idx & 63;
        int t = f >> 2, c = f & 3;
        int q = lane >> 4, nn = lane & 15;
        #pragma unroll
        for (int j = 0; j < 8; ++j) {
            unsigned u = __float_as_uint(W[(c * 32 + q * 8 + j) * 128 + t * 16 + nn]);
            u += 0x7fffu + ((u >> 16) & 1u);
            wp[idx * 8 + j] = (unsigned short)(u >> 16);
        }
    }
}

// hbuf8 row r (fp8) = fp8( dinv[r] * (x[r] @ W) )  -- pre-scaled; row N = zeros (dinv=0)
__global__ __launch_bounds__(256) void gemm_mfma(const void* __restrict__ xs,
                                                 const void* __restrict__ xt,
                                                 const unsigned short* __restrict__ wp,
                                                 unsigned* __restrict__ hb,
                                                 const float* __restrict__ dinv,
                                                 int N, int in_bf16) {
    int d = blockIdx.y;
    const void* xin = d ? xt : xs;
    unsigned* out = hb + (size_t)d * (N + 1) * 32;
    const float* dv = dinv + (size_t)d * (N + 1);
    __shared__ float cs[64 * 132];
    int tid = threadIdx.x;
    int wave = tid >> 6, lane = tid & 63;
    int quad = lane >> 4, nn = lane & 15;
    long long blockbase = (long long)blockIdx.x * 64;
    long long ar = blockbase + wave * 16 + nn;
    if (ar > N - 1) ar = N - 1;          // inputs have N rows

    bf16x8 a[4];
    if (in_bf16) {
        const uint4* xr = (const uint4*)((const unsigned short*)xin + ar * 128);
        #pragma unroll
        for (int c = 0; c < 4; ++c) {
            union { uint4 u; bf16x8 v; } cv;
            cv.u = xr[c * 4 + quad];
            a[c] = cv.v;
        }
    } else {
        const float4* xr = (const float4*)((const float*)xin + ar * 128);
        #pragma unroll
        for (int c = 0; c < 4; ++c) {
            float4 lo = xr[c * 8 + quad * 2];
            float4 hi = xr[c * 8 + quad * 2 + 1];
            union { bf16x8 v; unsigned u[4]; } au;
            au.u[0] = pack_bf16x2(lo.x, lo.y);
            au.u[1] = pack_bf16x2(lo.z, lo.w);
            au.u[2] = pack_bf16x2(hi.x, hi.y);
            au.u[3] = pack_bf16x2(hi.z, hi.w);
            a[c] = au.v;
        }
    }

    f32x4 acc[8];
    #pragma unroll
    for (int t = 0; t < 8; ++t) acc[t] = (f32x4){0.f, 0.f, 0.f, 0.f};
    const bf16x8* wf = (const bf16x8*)wp;
    #pragma unroll
    for (int t = 0; t < 8; ++t) {
        #pragma unroll
        for (int c = 0; c < 4; ++c) {
            bf16x8 b = wf[(t * 4 + c) * 64 + lane];
            acc[t] = __builtin_amdgcn_mfma_f32_16x16x32_bf16(a[c], b, acc[t], 0, 0, 0);
        }
    }

    #pragma unroll
    for (int t = 0; t < 8; ++t) {
        #pragma unroll
        for (int r = 0; r < 4; ++r)
            cs[(wave * 16 + quad * 4 + r) * 132 + t * 16 + nn] = acc[t][r];
    }
    __syncthreads();

    #pragma unroll
    for (int i = 0; i < 8; ++i) {
        int idx = tid + i * 256;
        int r = idx >> 5, c4 = idx & 31;
        long long row = blockbase + r;
        if (row <= N) {
            float s = dv[row];
            const float4 v = *(const float4*)&cs[r * 132 + c4 * 4];
            int pk = __builtin_amdgcn_cvt_pk_fp8_f32(v.x * s, v.y * s, 0, false);
            pk = __builtin_amdgcn_cvt_pk_fp8_f32(v.z * s, v.w * s, pk, true);
            out[row * 32 + c4] = (unsigned)pk;
        }
    }
}

// ---- agg layer 1: plain sum of pre-scaled fp8 rows over padded list; bf16+relu out ----
__global__ __launch_bounds__(256) void agg1_k(const unsigned* __restrict__ hb,
                                              const float* __restrict__ dinv,
                                              const int* __restrict__ offs,
                                              const int* __restrict__ csr,
                                              const float* __restrict__ bias,
                                              uint2* __restrict__ abuf, int N) {
    int d = blockIdx.y;
    const unsigned* hs = hb + (size_t)d * (N + 1) * 32;
    const float* dv = dinv + (size_t)d * (N + 1);
    const int* of = offs + (size_t)d * (N + 1);
    uint2* out = abuf + (size_t)d * N * 32;
    int wave = threadIdx.x >> 6, lane = threadIdx.x & 63;
    int node = blockIdx.x * 4 + wave;
    if (node >= N) return;
    int half = lane >> 5, li = lane & 31;
    float a0 = 0.f, a1 = 0.f, a2 = 0.f, a3 = 0.f;
    int e0 = of[node], e1 = of[node + 1];
    for (int e = e0; e < e1; e += 8) {
        int idx[4];
        #pragma unroll
        for (int j = 0; j < 4; ++j) idx[j] = csr[e + 2 * j + half];
        unsigned u[4];
        #pragma unroll
        for (int j = 0; j < 4; ++j) u[j] = hs[((unsigned)idx[j] << 5) | li];
        #pragma unroll
        for (int j = 0; j < 4; ++j) {
            f32x2 lo = __builtin_amdgcn_cvt_pk_f32_fp8((int)u[j], false);
            f32x2 hi = __builtin_amdgcn_cvt_pk_f32_fp8((int)u[j], true);
            a0 += lo[0]; a1 += lo[1]; a2 += hi[0]; a3 += hi[1];
        }
    }
    a0 += __shfl_xor(a0, 32);
    a1 += __shfl_xor(a1, 32);
    a2 += __shfl_xor(a2, 32);
    a3 += __shfl_xor(a3, 32);
    if (half == 0) {
        float di = dv[node];
        float4 b4 = ((const float4*)bias)[li];
        float o0 = fmaxf(fmaf(di, a0, b4.x), 0.f);
        float o1 = fmaxf(fmaf(di, a1, b4.y), 0.f);
        float o2 = fmaxf(fmaf(di, a2, b4.z), 0.f);
        float o3 = fmaxf(fmaf(di, a3, b4.w), 0.f);
        out[(size_t)node * 32 + li] = make_uint2(pack_bf16x2(o0, o1), pack_bf16x2(o2, o3));
    }
}

// ---- agg layer 2 fused with per-node loss dots ----
__global__ __launch_bounds__(256) void agg2_k(const unsigned* __restrict__ hb,
                                              const float* __restrict__ dinv,
                                              const int* __restrict__ offs,
                                              const int* __restrict__ csr,
                                              const float* __restrict__ bias,
                                              const float* __restrict__ clsW,
                                              const float* __restrict__ duW,
                                              const float* __restrict__ diW,
                                              const int* __restrict__ nus,
                                              const int* __restrict__ nut,
                                              float2* __restrict__ nodeDots, int N) {
    int d = blockIdx.y;
    const unsigned* hs = hb + (size_t)d * (N + 1) * 32;
    const float* dv = dinv + (size_t)d * (N + 1);
    const int* of = offs + (size_t)d * (N + 1);
    float2* nd = nodeDots + (size_t)d * N;
    int nu = d ? nut[0] : nus[0];
    int wave = threadIdx.x >> 6, lane = threadIdx.x & 63;
    int node = blockIdx.x * 4 + wave;
    if (node >= N) return;
    int half = lane >> 5, li = lane & 31;
    float a0 = 0.f, a1 = 0.f, a2 = 0.f, a3 = 0.f;
    int e0 = of[node], e1 = of[node + 1];
    for (int e = e0; e < e1; e += 8) {
        int idx[4];
        #pragma unroll
        for (int j = 0; j < 4; ++j) idx[j] = csr[e + 2 * j + half];
        unsigned u[4];
        #pragma unroll
        for (int j = 0; j < 4; ++j) u[j] = hs[((unsigned)idx[j] << 5) | li];
        #pragma unroll
        for (int j = 0; j < 4; ++j) {
            f32x2 lo = __builtin_amdgcn_cvt_pk_f32_fp8((int)u[j], false);
            f32x2 hi = __builtin_amdgcn_cvt_pk_f32_fp8((int)u[j], true);
            a0 += lo[0]; a1 += lo[1]; a2 += hi[0]; a3 += hi[1];
        }
    }
    a0 += __shfl_xor(a0, 32);
    a1 += __shfl_xor(a1, 32);
    a2 += __shfl_xor(a2, 32);
    a3 += __shfl_xor(a3, 32);
    float di = dv[node];
    float4 b4 = ((const float4*)bias)[li];
    float o0 = fmaf(di, a0, b4.x);
    float o1 = fmaf(di, a1, b4.y);
    float o2 = fmaf(di, a2, b4.z);
    float o3 = fmaf(di, a3, b4.w);
    int sel = (node >= nu) ? 1 : 0;
    float4 wA = ((const float4*)clsW)[sel * 32 + li];
    float4 wB = ((const float4*)(sel ? diW : duW))[li];
    float p = o0 * wA.x + o1 * wA.y + o2 * wA.z + o3 * wA.w;
    float q = o0 * wB.x + o1 * wB.y + o2 * wB.z + o3 * wB.w;
    #pragma unroll
    for (int o = 16; o > 0; o >>= 1) {
        p += __shfl_xor(p, o);
        q += __shfl_xor(q, o);
    }
    if (lane == 0) nd[node] = make_float2(p, q);
}

// ---- pair loss ----
__global__ __launch_bounds__(256) void loss_k(const float2* __restrict__ nodeDots,
                                              const int* __restrict__ us, const int* __restrict__ is_,
                                              const int* __restrict__ ls,
                                              const int* __restrict__ ut, const int* __restrict__ it,
                                              const int* __restrict__ lt,
                                              const float* __restrict__ clsb,
                                              const float* __restrict__ dub,
                                              const float* __restrict__ dib,
                                              const int* __restrict__ nus,
                                              const int* __restrict__ nut,
                                              float* __restrict__ accum, int Bn, int N) {
    int d = blockIdx.y;
    const float2* nd = nodeDots + (size_t)d * N;
    const int* users = d ? ut : us;
    const int* items = d ? it : is_;
    const int* labels = d ? lt : ls;
    int nu = d ? nut[0] : nus[0];
    float* acc = accum + 3 * d;
    int k = blockIdx.x * 256 + threadIdx.x;
    float bce = 0.f, cu = 0.f, ci = 0.f;
    if (k < Bn) {
        int u = users[k];
        int t = items[k] + nu;
        float2 ud = nd[u];
        float2 id = nd[t];
        float z = ud.x + id.x + clsb[0];
        float y = (float)labels[k];
        float sp = fmaxf(z, 0.f) + log1pf(expf(-fabsf(z)));
        bce = sp - y * z;
        cu = 1.f / (1.f + expf(-(ud.y + dub[0])));
        ci = 1.f / (1.f + expf(-(id.y + dib[0])));
    }
    #pragma unroll
    for (int o = 32; o > 0; o >>= 1) {
        bce += __shfl_xor(bce, o);
        cu += __shfl_xor(cu, o);
        ci += __shfl_xor(ci, o);
    }
    __shared__ float sh[12];
    int lane = threadIdx.x & 63, wave = threadIdx.x >> 6;
    if (lane == 0) { sh[wave * 3 + 0] = bce; sh[wave * 3 + 1] = cu; sh[wave * 3 + 2] = ci; }
    __syncthreads();
    if (threadIdx.x < 3) {
        float v = sh[threadIdx.x] + sh[3 + threadIdx.x] + sh[6 + threadIdx.x] + sh[9 + threadIdx.x];
        atomicAdd(&acc[threadIdx.x], v);
    }
}

__global__ void finalize_k(const float* __restrict__ accum, float* __restrict__ out, float invB) {
    if (threadIdx.x == 0 && blockIdx.x == 0) {
        float clf = (accum[0] + accum[3]) * invB;
        float dom = fabsf((accum[1] - accum[4]) * invB) + fabsf((accum[2] - accum[5]) * invB);
        out[0] = clf + dom;
    }
}

extern "C" void kernel_launch(void* const* d_in, const int* in_sizes, int n_in,
                              void* d_out, int out_size, void* d_ws, size_t ws_size,
                              hipStream_t stream) {
    const float* feats_s = (const float*)d_in[0];
    const float* feats_t = (const float*)d_in[1];
    const float* W1   = (const float*)d_in[2];
    const float* b1   = (const float*)d_in[3];
    const float* W2   = (const float*)d_in[4];
    const float* b2   = (const float*)d_in[5];
    const float* clsW = (const float*)d_in[6];
    const float* clsb = (const float*)d_in[7];
    const float* duW  = (const float*)d_in[8];
    const float* dub  = (const float*)d_in[9];
    const float* diW  = (const float*)d_in[10];
    const float* dib  = (const float*)d_in[11];

    int N = in_sizes[0] / D;
    int E = in_sizes[12];
    int B = in_sizes[16];
    int nb = (N + 255) >> 8;          // real buckets per domain (<= NB)
    int M = 2 * (N + 1);              // padded-degree scan length
    int nb2 = (M + 1023) / 1024;

    char* ws = (char*)d_ws;
    size_t off = 0;
    auto alloc = [&](size_t bytes) -> void* {
        void* p = ws + off;
        off += (bytes + 255) & ~(size_t)255;
        return p;
    };
    int*      bcnt   = (int*)  alloc(2 * NB * 4);
    int*      bbase  = (int*)  alloc((2 * NB + 1) * 4);
    int*      cursor = (int*)  alloc(2 * NB * 4);
    int*      ncnt   = (int*)  alloc((size_t)M * 4);
    float*    dinv   = (float*)alloc((size_t)M * 4);
    int*      pval   = (int*)  alloc((size_t)M * 4);
    int*      offsp  = (int*)  alloc((size_t)M * 4);
    int*      bsum   = (int*)  alloc((size_t)nb2 * 4 + 256);
    unsigned* pairs  = (unsigned*)alloc((size_t)2 * E * 4);
    int*      csr    = (int*)  alloc((size_t)2 * (E + 8 * (N + 1)) * 4);
    unsigned* hbuf8  = (unsigned*)alloc((size_t)2 * (N + 1) * 128);   // fp8 pre-scaled rows
    unsigned* abuf   = (unsigned*)alloc((size_t)2 * N * 256);         // bf16 agg1 rows
    float2*   nodeDots = (float2*)alloc((size_t)2 * N * 8);
    unsigned short* wp1 = (unsigned short*)alloc(16384 * 2);
    unsigned short* wp2 = (unsigned short*)alloc(16384 * 2);
    float*    accum  = (float*)alloc(128);

    hipMemsetAsync(accum, 0, 6 * sizeof(float), stream);
    hipMemsetAsync(bcnt, 0, 2 * NB * 4, stream);
    hipMemsetAsync(ncnt, 0, (size_t)M * 4, stream);

    const int* esrc_s = (const int*)d_in[12];
    const int* edst_s = (const int*)d_in[13];
    const int* esrc_t = (const int*)d_in[14];
    const int* edst_t = (const int*)d_in[15];
    const int* user_s = (const int*)d_in[16];
    const int* item_s = (const int*)d_in[17];
    const int* lab_s  = (const int*)d_in[18];
    const int* user_t = (const int*)d_in[19];
    const int* item_t = (const int*)d_in[20];
    const int* lab_t  = (const int*)d_in[21];
    const int* nup_s  = (const int*)d_in[22];
    const int* nup_t  = (const int*)d_in[23];

    packW_k<<<2, 256, 0, stream>>>(W1, W2, wp1, wp2);

    bhist_k<<<dim3(512, 2), 256, 0, stream>>>(edst_s, edst_t, bcnt, ncnt, E, N);
    scanB_k<<<1, 1024, 0, stream>>>(bcnt, bbase, cursor);
    deg_k<<<dim3((N + 256) / 256, 2), 256, 0, stream>>>(ncnt, dinv, pval, N);
    scan_bsum_k<<<nb2, 256, 0, stream>>>(pval, bsum, M);
    scan_serial_k<<<1, 64, 0, stream>>>(bsum, nb2);
    scan_final_k<<<nb2, 256, 0, stream>>>(pval, bsum, offsp, M);
    bin_k<<<dim3((E + 2047) / 2048, 2), 256, 0, stream>>>(esrc_s, edst_s, esrc_t, edst_t,
                                                          cursor, pairs, E);
    csrb_k<<<dim3(nb, 2), 256, 0, stream>>>(pairs, bbase, offsp, csr, N);

    int ngb = (N + 64) / 64;   // covers rows 0..N (incl. sentinel row N)
    gemm_mfma<<<dim3(ngb, 2), 256, 0, stream>>>(feats_s, feats_t, wp1, hbuf8, dinv, N, 0);
    agg1_k<<<dim3((N + 3) / 4, 2), 256, 0, stream>>>(hbuf8, dinv, offsp, csr, b1,
                                                     (uint2*)abuf, N);
    gemm_mfma<<<dim3(ngb, 2), 256, 0, stream>>>(abuf, abuf + (size_t)N * 64, wp2,
                                                hbuf8, dinv, N, 1);
    agg2_k<<<dim3((N + 3) / 4, 2), 256, 0, stream>>>(hbuf8, dinv, offsp, csr, b2,
                                                     clsW, duW, diW, nup_s, nup_t,
                                                     nodeDots, N);
    loss_k<<<dim3((B + 255) / 256, 2), 256, 0, stream>>>(nodeDots,
                                                         user_s, item_s, lab_s,
                                                         user_t, item_t, lab_t,
                                                         clsb, dub, dib, nup_s, nup_t,
                                                         accum, B, N);
    finalize_k<<<1, 64, 0, stream>>>(accum, (float*)d_out, 1.0f / (float)B);
}

// Round 8
// 511.382 us; speedup vs baseline: 1.2808x; 1.2808x over previous
//
#include <hip/hip_runtime.h>

#define D 128
#define NB 512   // bucket slots per domain (bucket = node >> 8)

typedef __attribute__((ext_vector_type(8))) short bf16x8;
typedef __attribute__((ext_vector_type(4))) float f32x4;
typedef __attribute__((ext_vector_type(2))) float f32x2;

static __device__ inline unsigned pack_bf16x2(float a, float b) {
    unsigned ua = __float_as_uint(a);
    unsigned ub = __float_as_uint(b);
    ua += 0x7fffu + ((ua >> 16) & 1u);
    ub += 0x7fffu + ((ub >> 16) & 1u);
    return (ua >> 16) | (ub & 0xffff0000u);
}

// ---- bucket histogram (LDS only — no global node atomics) ----
__global__ __launch_bounds__(256) void bh_k(const int* __restrict__ dst_s,
                                            const int* __restrict__ dst_t,
                                            int* __restrict__ bcnt, int E) {
    int d = blockIdx.y;
    const int* dst = d ? dst_t : dst_s;
    __shared__ int h[NB];
    for (int i = threadIdx.x; i < NB; i += 256) h[i] = 0;
    __syncthreads();
    int stride = gridDim.x * 256;
    for (int e = blockIdx.x * 256 + threadIdx.x; e < E; e += stride)
        atomicAdd(&h[dst[e] >> 8], 1);
    __syncthreads();
    for (int i = threadIdx.x; i < NB; i += 256)
        if (h[i]) atomicAdd(&bcnt[d * NB + i], h[i]);
}

// ---- exclusive scan of 1024 bucket counts (both domains, one block) ----
__global__ __launch_bounds__(1024) void scanB_k(const int* __restrict__ bcnt,
                                                int* __restrict__ bbase,
                                                int* __restrict__ cursor) {
    __shared__ int sh[1024];
    int t = threadIdx.x;
    int v = bcnt[t];
    sh[t] = v;
    __syncthreads();
    for (int o = 1; o < 1024; o <<= 1) {
        int x = (t >= o) ? sh[t - o] : 0;
        __syncthreads();
        sh[t] += x;
        __syncthreads();
    }
    int ex = sh[t] - v;
    bbase[t] = ex; cursor[t] = ex;
    if (t == 1023) bbase[1024] = sh[1023];
}

// ---- bin edges into bucket regions: src | (dst&255)<<24 ----
__global__ __launch_bounds__(256) void bin_k(const int* __restrict__ src_s,
                                             const int* __restrict__ dst_s,
                                             const int* __restrict__ src_t,
                                             const int* __restrict__ dst_t,
                                             int* __restrict__ cursor,
                                             unsigned* __restrict__ pairs, int E) {
    int d = blockIdx.y;
    const int* src = d ? src_t : src_s;
    const int* dst = d ? dst_t : dst_s;
    int* cur = cursor + d * NB;
    __shared__ int h[NB];
    __shared__ int gb[NB];
    int t0 = blockIdx.x * 2048;
    if (t0 >= E) return;
    for (int i = threadIdx.x; i < NB; i += 256) h[i] = 0;
    __syncthreads();
    int rank[8]; unsigned pk[8]; short bk[8];
    #pragma unroll
    for (int j = 0; j < 8; ++j) {
        int e = t0 + j * 256 + threadIdx.x;
        if (e < E) {
            int dd = dst[e], s = src[e];
            bk[j] = (short)(dd >> 8);
            pk[j] = (unsigned)s | ((unsigned)(dd & 255) << 24);
            rank[j] = atomicAdd(&h[dd >> 8], 1);
        } else bk[j] = -1;
    }
    __syncthreads();
    for (int i = threadIdx.x; i < NB; i += 256)
        gb[i] = h[i] ? atomicAdd(&cur[i], h[i]) : 0;
    __syncthreads();
    #pragma unroll
    for (int j = 0; j < 8; ++j)
        if (bk[j] >= 0) pairs[gb[bk[j]] + rank[j]] = pk[j];
}

// ---- per-bucket: LDS node hist -> nspan/dinv, scatter into padded CSR ----
// bucket g's CSR region starts at closed-form cbase = bbase[g] + g*2048
// (capacity bound: sum pad8(deg+1) <= edges_in_bucket + 256*8)
__global__ __launch_bounds__(256) void csrb_k(const unsigned* __restrict__ pairs,
                                              const int* __restrict__ bbase,
                                              int2* __restrict__ nspan,
                                              float* __restrict__ dinv,
                                              int* __restrict__ csr, int N) {
    int d = blockIdx.y, bx = blockIdx.x, t = threadIdx.x;
    int g = d * NB + bx;
    int e0 = bbase[g], e1 = bbase[g + 1];
    int cbase = e0 + g * 2048;
    float* dv = dinv + (size_t)d * (N + 1);
    int2* ns = nspan + (size_t)d * N;
    __shared__ int lh[256];
    __shared__ int lex[256];
    __shared__ int lc[256];
    lh[t] = 0; lc[t] = 0;
    __syncthreads();
    for (int e = e0 + t; e < e1; e += 256)
        atomicAdd(&lh[pairs[e] >> 24], 1);
    __syncthreads();
    int node = (bx << 8) + t;
    bool valid = node < N;
    int deg = lh[t];
    int pdeg = valid ? (((deg + 8) >> 3) << 3) : 0;   // pad8(deg + self)
    lex[t] = pdeg;
    __syncthreads();
    for (int o = 1; o < 256; o <<= 1) {
        int x = (t >= o) ? lex[t - o] : 0;
        __syncthreads();
        lex[t] += x;
        __syncthreads();
    }
    int start = cbase + lex[t] - pdeg;
    if (valid) {
        ns[node] = make_int2(start, start + pdeg);
        dv[node] = rsqrtf((float)(deg + 1));
    }
    lex[t] = start;               // own-slot overwrite; cross-thread reads after barrier
    __syncthreads();
    for (int e = e0 + t; e < e1; e += 256) {
        unsigned p = pairs[e];
        int dn = p >> 24;
        int rank = atomicAdd(&lc[dn], 1);
        csr[lex[dn] + rank] = (int)(p & 0xffffffu);
    }
    __syncthreads();
    if (valid) {
        int b = lex[t];
        csr[b + deg] = node;                            // self (pre-scaled row IS the self term)
        for (int k = deg + 1; k < pdeg; ++k) csr[b + k] = N;   // sentinel zero-row
    }
    if (bx == 0 && t == 0) dv[N] = 0.f;                 // sentinel row scale
}

// ================= MFMA GEMM =================
__global__ __launch_bounds__(256) void packW_k(const float* __restrict__ W1,
                                               const float* __restrict__ W2,
                                               unsigned short* __restrict__ wp1,
                                               unsigned short* __restrict__ wp2) {
    const float* W = blockIdx.x ? W2 : W1;
    unsigned short* wp = blockIdx.x ? wp2 : wp1;
    for (int idx = threadIdx.x; idx < 2048; idx += 256) {
        int f = idx >> 6, lane = idx & 63;
        int t = f >> 2, c = f & 3;
        int q = lane >> 4, nn = lane & 15;
        #pragma unroll
        for (int j = 0; j < 8; ++j) {
            unsigned u = __float_as_uint(W[(c * 32 + q * 8 + j) * 128 + t * 16 + nn]);
            u += 0x7fffu + ((u >> 16) & 1u);
            wp[idx * 8 + j] = (unsigned short)(u >> 16);
        }
    }
}

// hbuf8 row r (fp8) = fp8( dinv[r] * (x[r] @ W) )  -- pre-scaled; row N = zeros (dinv=0)
__global__ __launch_bounds__(256) void gemm_mfma(const void* __restrict__ xs,
                                                 const void* __restrict__ xt,
                                                 const unsigned short* __restrict__ wp,
                                                 unsigned* __restrict__ hb,
                                                 const float* __restrict__ dinv,
                                                 int N, int in_bf16) {
    int d = blockIdx.y;
    const void* xin = d ? xt : xs;
    unsigned* out = hb + (size_t)d * (N + 1) * 32;
    const float* dv = dinv + (size_t)d * (N + 1);
    __shared__ float cs[64 * 132];
    int tid = threadIdx.x;
    int wave = tid >> 6, lane = tid & 63;
    int quad = lane >> 4, nn = lane & 15;
    long long blockbase = (long long)blockIdx.x * 64;
    long long ar = blockbase + wave * 16 + nn;
    if (ar > N - 1) ar = N - 1;          // inputs have N rows

    bf16x8 a[4];
    if (in_bf16) {
        const uint4* xr = (const uint4*)((const unsigned short*)xin + ar * 128);
        #pragma unroll
        for (int c = 0; c < 4; ++c) {
            union { uint4 u; bf16x8 v; } cv;
            cv.u = xr[c * 4 + quad];
            a[c] = cv.v;
        }
    } else {
        const float4* xr = (const float4*)((const float*)xin + ar * 128);
        #pragma unroll
        for (int c = 0; c < 4; ++c) {
            float4 lo = xr[c * 8 + quad * 2];
            float4 hi = xr[c * 8 + quad * 2 + 1];
            union { bf16x8 v; unsigned u[4]; } au;
            au.u[0] = pack_bf16x2(lo.x, lo.y);
            au.u[1] = pack_bf16x2(lo.z, lo.w);
            au.u[2] = pack_bf16x2(hi.x, hi.y);
            au.u[3] = pack_bf16x2(hi.z, hi.w);
            a[c] = au.v;
        }
    }

    f32x4 acc[8];
    #pragma unroll
    for (int t = 0; t < 8; ++t) acc[t] = (f32x4){0.f, 0.f, 0.f, 0.f};
    const bf16x8* wf = (const bf16x8*)wp;
    #pragma unroll
    for (int t = 0; t < 8; ++t) {
        #pragma unroll
        for (int c = 0; c < 4; ++c) {
            bf16x8 b = wf[(t * 4 + c) * 64 + lane];
            acc[t] = __builtin_amdgcn_mfma_f32_16x16x32_bf16(a[c], b, acc[t], 0, 0, 0);
        }
    }

    #pragma unroll
    for (int t = 0; t < 8; ++t) {
        #pragma unroll
        for (int r = 0; r < 4; ++r)
            cs[(wave * 16 + quad * 4 + r) * 132 + t * 16 + nn] = acc[t][r];
    }
    __syncthreads();

    #pragma unroll
    for (int i = 0; i < 8; ++i) {
        int idx = tid + i * 256;
        int r = idx >> 5, c4 = idx & 31;
        long long row = blockbase + r;
        if (row <= N) {
            float s = dv[row];
            const float4 v = *(const float4*)&cs[r * 132 + c4 * 4];
            int pk = __builtin_amdgcn_cvt_pk_fp8_f32(v.x * s, v.y * s, 0, false);
            pk = __builtin_amdgcn_cvt_pk_fp8_f32(v.z * s, v.w * s, pk, true);
            out[row * 32 + c4] = (unsigned)pk;
        }
    }
}

// ---- agg layer 1: plain sum of pre-scaled fp8 rows over padded list; bf16+relu out ----
__global__ __launch_bounds__(256) void agg1_k(const unsigned* __restrict__ hb,
                                              const float* __restrict__ dinv,
                                              const int2* __restrict__ nspan,
                                              const int* __restrict__ csr,
                                              const float* __restrict__ bias,
                                              uint2* __restrict__ abuf, int N) {
    int d = blockIdx.y;
    const unsigned* hs = hb + (size_t)d * (N + 1) * 32;
    const float* dv = dinv + (size_t)d * (N + 1);
    const int2* ns = nspan + (size_t)d * N;
    uint2* out = abuf + (size_t)d * N * 32;
    int wave = threadIdx.x >> 6, lane = threadIdx.x & 63;
    int node = blockIdx.x * 4 + wave;
    if (node >= N) return;
    int half = lane >> 5, li = lane & 31;
    float a0 = 0.f, a1 = 0.f, a2 = 0.f, a3 = 0.f;
    int2 sp = ns[node];
    for (int e = sp.x; e < sp.y; e += 8) {
        int idx[4];
        #pragma unroll
        for (int j = 0; j < 4; ++j) idx[j] = csr[e + 2 * j + half];
        unsigned u[4];
        #pragma unroll
        for (int j = 0; j < 4; ++j) u[j] = hs[((unsigned)idx[j] << 5) | li];
        #pragma unroll
        for (int j = 0; j < 4; ++j) {
            f32x2 lo = __builtin_amdgcn_cvt_pk_f32_fp8((int)u[j], false);
            f32x2 hi = __builtin_amdgcn_cvt_pk_f32_fp8((int)u[j], true);
            a0 += lo[0]; a1 += lo[1]; a2 += hi[0]; a3 += hi[1];
        }
    }
    a0 += __shfl_xor(a0, 32);
    a1 += __shfl_xor(a1, 32);
    a2 += __shfl_xor(a2, 32);
    a3 += __shfl_xor(a3, 32);
    if (half == 0) {
        float di = dv[node];
        float4 b4 = ((const float4*)bias)[li];
        float o0 = fmaxf(fmaf(di, a0, b4.x), 0.f);
        float o1 = fmaxf(fmaf(di, a1, b4.y), 0.f);
        float o2 = fmaxf(fmaf(di, a2, b4.z), 0.f);
        float o3 = fmaxf(fmaf(di, a3, b4.w), 0.f);
        out[(size_t)node * 32 + li] = make_uint2(pack_bf16x2(o0, o1), pack_bf16x2(o2, o3));
    }
}

// ---- agg layer 2 fused with per-node loss dots ----
__global__ __launch_bounds__(256) void agg2_k(const unsigned* __restrict__ hb,
                                              const float* __restrict__ dinv,
                                              const int2* __restrict__ nspan,
                                              const int* __restrict__ csr,
                                              const float* __restrict__ bias,
                                              const float* __restrict__ clsW,
                                              const float* __restrict__ duW,
                                              const float* __restrict__ diW,
                                              const int* __restrict__ nus,
                                              const int* __restrict__ nut,
                                              float2* __restrict__ nodeDots, int N) {
    int d = blockIdx.y;
    const unsigned* hs = hb + (size_t)d * (N + 1) * 32;
    const float* dv = dinv + (size_t)d * (N + 1);
    const int2* ns = nspan + (size_t)d * N;
    float2* nd = nodeDots + (size_t)d * N;
    int nu = d ? nut[0] : nus[0];
    int wave = threadIdx.x >> 6, lane = threadIdx.x & 63;
    int node = blockIdx.x * 4 + wave;
    if (node >= N) return;
    int half = lane >> 5, li = lane & 31;
    float a0 = 0.f, a1 = 0.f, a2 = 0.f, a3 = 0.f;
    int2 sp = ns[node];
    for (int e = sp.x; e < sp.y; e += 8) {
        int idx[4];
        #pragma unroll
        for (int j = 0; j < 4; ++j) idx[j] = csr[e + 2 * j + half];
        unsigned u[4];
        #pragma unroll
        for (int j = 0; j < 4; ++j) u[j] = hs[((unsigned)idx[j] << 5) | li];
        #pragma unroll
        for (int j = 0; j < 4; ++j) {
            f32x2 lo = __builtin_amdgcn_cvt_pk_f32_fp8((int)u[j], false);
            f32x2 hi = __builtin_amdgcn_cvt_pk_f32_fp8((int)u[j], true);
            a0 += lo[0]; a1 += lo[1]; a2 += hi[0]; a3 += hi[1];
        }
    }
    a0 += __shfl_xor(a0, 32);
    a1 += __shfl_xor(a1, 32);
    a2 += __shfl_xor(a2, 32);
    a3 += __shfl_xor(a3, 32);
    float di = dv[node];
    float4 b4 = ((const float4*)bias)[li];
    float o0 = fmaf(di, a0, b4.x);
    float o1 = fmaf(di, a1, b4.y);
    float o2 = fmaf(di, a2, b4.z);
    float o3 = fmaf(di, a3, b4.w);
    int sel = (node >= nu) ? 1 : 0;
    float4 wA = ((const float4*)clsW)[sel * 32 + li];
    float4 wB = ((const float4*)(sel ? diW : duW))[li];
    float p = o0 * wA.x + o1 * wA.y + o2 * wA.z + o3 * wA.w;
    float q = o0 * wB.x + o1 * wB.y + o2 * wB.z + o3 * wB.w;
    #pragma unroll
    for (int o = 16; o > 0; o >>= 1) {
        p += __shfl_xor(p, o);
        q += __shfl_xor(q, o);
    }
    if (lane == 0) nd[node] = make_float2(p, q);
}

// ---- pair loss ----
__global__ __launch_bounds__(256) void loss_k(const float2* __restrict__ nodeDots,
                                              const int* __restrict__ us, const int* __restrict__ is_,
                                              const int* __restrict__ ls,
                                              const int* __restrict__ ut, const int* __restrict__ it,
                                              const int* __restrict__ lt,
                                              const float* __restrict__ clsb,
                                              const float* __restrict__ dub,
                                              const float* __restrict__ dib,
                                              const int* __restrict__ nus,
                                              const int* __restrict__ nut,
                                              float* __restrict__ accum, int Bn, int N) {
    int d = blockIdx.y;
    const float2* nd = nodeDots + (size_t)d * N;
    const int* users = d ? ut : us;
    const int* items = d ? it : is_;
    const int* labels = d ? lt : ls;
    int nu = d ? nut[0] : nus[0];
    float* acc = accum + 3 * d;
    int k = blockIdx.x * 256 + threadIdx.x;
    float bce = 0.f, cu = 0.f, ci = 0.f;
    if (k < Bn) {
        int u = users[k];
        int t = items[k] + nu;
        float2 ud = nd[u];
        float2 id = nd[t];
        float z = ud.x + id.x + clsb[0];
        float y = (float)labels[k];
        float sp = fmaxf(z, 0.f) + log1pf(expf(-fabsf(z)));
        bce = sp - y * z;
        cu = 1.f / (1.f + expf(-(ud.y + dub[0])));
        ci = 1.f / (1.f + expf(-(id.y + dib[0])));
    }
    #pragma unroll
    for (int o = 32; o > 0; o >>= 1) {
        bce += __shfl_xor(bce, o);
        cu += __shfl_xor(cu, o);
        ci += __shfl_xor(ci, o);
    }
    __shared__ float sh[12];
    int lane = threadIdx.x & 63, wave = threadIdx.x >> 6;
    if (lane == 0) { sh[wave * 3 + 0] = bce; sh[wave * 3 + 1] = cu; sh[wave * 3 + 2] = ci; }
    __syncthreads();
    if (threadIdx.x < 3) {
        float v = sh[threadIdx.x] + sh[3 + threadIdx.x] + sh[6 + threadIdx.x] + sh[9 + threadIdx.x];
        atomicAdd(&acc[threadIdx.x], v);
    }
}

__global__ void finalize_k(const float* __restrict__ accum, float* __restrict__ out, float invB) {
    if (threadIdx.x == 0 && blockIdx.x == 0) {
        float clf = (accum[0] + accum[3]) * invB;
        float dom = fabsf((accum[1] - accum[4]) * invB) + fabsf((accum[2] - accum[5]) * invB);
        out[0] = clf + dom;
    }
}

extern "C" void kernel_launch(void* const* d_in, const int* in_sizes, int n_in,
                              void* d_out, int out_size, void* d_ws, size_t ws_size,
                              hipStream_t stream) {
    const float* feats_s = (const float*)d_in[0];
    const float* feats_t = (const float*)d_in[1];
    const float* W1   = (const float*)d_in[2];
    const float* b1   = (const float*)d_in[3];
    const float* W2   = (const float*)d_in[4];
    const float* b2   = (const float*)d_in[5];
    const float* clsW = (const float*)d_in[6];
    const float* clsb = (const float*)d_in[7];
    const float* duW  = (const float*)d_in[8];
    const float* dub  = (const float*)d_in[9];
    const float* diW  = (const float*)d_in[10];
    const float* dib  = (const float*)d_in[11];

    int N = in_sizes[0] / D;
    int E = in_sizes[12];
    int B = in_sizes[16];
    int nb = (N + 255) >> 8;          // real buckets per domain (<= NB)

    char* ws = (char*)d_ws;
    size_t off = 0;
    auto alloc = [&](size_t bytes) -> void* {
        void* p = ws + off;
        off += (bytes + 255) & ~(size_t)255;
        return p;
    };
    int*      bcnt   = (int*)  alloc(2 * NB * 4);
    int*      bbase  = (int*)  alloc((2 * NB + 1) * 4);
    int*      cursor = (int*)  alloc(2 * NB * 4);
    float*    dinv   = (float*)alloc((size_t)2 * (N + 1) * 4);
    int2*     nspan  = (int2*) alloc((size_t)2 * N * 8);
    unsigned* pairs  = (unsigned*)alloc((size_t)2 * E * 4);
    int*      csr    = (int*)  alloc(((size_t)2 * E + 2 * NB * 2048) * 4);
    unsigned* hbuf8  = (unsigned*)alloc((size_t)2 * (N + 1) * 128);   // fp8 pre-scaled rows
    unsigned* abuf   = (unsigned*)alloc((size_t)2 * N * 256);         // bf16 agg1 rows
    float2*   nodeDots = (float2*)alloc((size_t)2 * N * 8);
    unsigned short* wp1 = (unsigned short*)alloc(16384 * 2);
    unsigned short* wp2 = (unsigned short*)alloc(16384 * 2);
    float*    accum  = (float*)alloc(128);

    hipMemsetAsync(accum, 0, 6 * sizeof(float), stream);
    hipMemsetAsync(bcnt, 0, 2 * NB * 4, stream);

    const int* esrc_s = (const int*)d_in[12];
    const int* edst_s = (const int*)d_in[13];
    const int* esrc_t = (const int*)d_in[14];
    const int* edst_t = (const int*)d_in[15];
    const int* user_s = (const int*)d_in[16];
    const int* item_s = (const int*)d_in[17];
    const int* lab_s  = (const int*)d_in[18];
    const int* user_t = (const int*)d_in[19];
    const int* item_t = (const int*)d_in[20];
    const int* lab_t  = (const int*)d_in[21];
    const int* nup_s  = (const int*)d_in[22];
    const int* nup_t  = (const int*)d_in[23];

    packW_k<<<2, 256, 0, stream>>>(W1, W2, wp1, wp2);

    bh_k<<<dim3(512, 2), 256, 0, stream>>>(edst_s, edst_t, bcnt, E);
    scanB_k<<<1, 1024, 0, stream>>>(bcnt, bbase, cursor);
    bin_k<<<dim3((E + 2047) / 2048, 2), 256, 0, stream>>>(esrc_s, edst_s, esrc_t, edst_t,
                                                          cursor, pairs, E);
    csrb_k<<<dim3(nb, 2), 256, 0, stream>>>(pairs, bbase, nspan, dinv, csr, N);

    int ngb = (N + 64) / 64;   // covers rows 0..N (incl. sentinel row N)
    gemm_mfma<<<dim3(ngb, 2), 256, 0, stream>>>(feats_s, feats_t, wp1, hbuf8, dinv, N, 0);
    agg1_k<<<dim3((N + 3) / 4, 2), 256, 0, stream>>>(hbuf8, dinv, nspan, csr, b1,
                                                     (uint2*)abuf, N);
    gemm_mfma<<<dim3(ngb, 2), 256, 0, stream>>>(abuf, abuf + (size_t)N * 64, wp2,
                                                hbuf8, dinv, N, 1);
    agg2_k<<<dim3((N + 3) / 4, 2), 256, 0, stream>>>(hbuf8, dinv, nspan, csr, b2,
                                                     clsW, duW, diW, nup_s, nup_t,
                                                     nodeDots, N);
    loss_k<<<dim3((B + 255) / 256, 2), 256, 0, stream>>>(nodeDots,
                                                         user_s, item_s, lab_s,
                                                         user_t, item_t, lab_t,
                                                         clsb, dub, dib, nup_s, nup_t,
                                                         accum, B, N);
    finalize_k<<<1, 64, 0, stream>>>(accum, (float*)d_out, 1.0f / (float)B);
}

// Round 9
// 493.776 us; speedup vs baseline: 1.3264x; 1.0357x over previous
//
#include <hip/hip_runtime.h>

#define D 128
#define NB 512   // bucket slots per domain (bucket = node >> 8)
#define BSLACK 4112   // per-bucket CSR slack: 256*16 pad + 15 align + 1

typedef __attribute__((ext_vector_type(8))) short bf16x8;
typedef __attribute__((ext_vector_type(4))) float f32x4;
typedef __attribute__((ext_vector_type(2))) float f32x2;

static __device__ inline unsigned pack_bf16x2(float a, float b) {
    unsigned ua = __float_as_uint(a);
    unsigned ub = __float_as_uint(b);
    ua += 0x7fffu + ((ua >> 16) & 1u);
    ub += 0x7fffu + ((ub >> 16) & 1u);
    return (ua >> 16) | (ub & 0xffff0000u);
}

// ---- bucket histogram (LDS only) ----
__global__ __launch_bounds__(256) void bh_k(const int* __restrict__ dst_s,
                                            const int* __restrict__ dst_t,
                                            int* __restrict__ bcnt, int E) {
    int d = blockIdx.y;
    const int* dst = d ? dst_t : dst_s;
    __shared__ int h[NB];
    for (int i = threadIdx.x; i < NB; i += 256) h[i] = 0;
    __syncthreads();
    int stride = gridDim.x * 256;
    for (int e = blockIdx.x * 256 + threadIdx.x; e < E; e += stride)
        atomicAdd(&h[dst[e] >> 8], 1);
    __syncthreads();
    for (int i = threadIdx.x; i < NB; i += 256)
        if (h[i]) atomicAdd(&bcnt[d * NB + i], h[i]);
}

// ---- exclusive scan of 1024 bucket counts ----
__global__ __launch_bounds__(1024) void scanB_k(const int* __restrict__ bcnt,
                                                int* __restrict__ bbase,
                                                int* __restrict__ cursor) {
    __shared__ int sh[1024];
    int t = threadIdx.x;
    int v = bcnt[t];
    sh[t] = v;
    __syncthreads();
    for (int o = 1; o < 1024; o <<= 1) {
        int x = (t >= o) ? sh[t - o] : 0;
        __syncthreads();
        sh[t] += x;
        __syncthreads();
    }
    int ex = sh[t] - v;
    bbase[t] = ex; cursor[t] = ex;
    if (t == 1023) bbase[1024] = sh[1023];
}

// ---- bin edges into bucket regions: src | (dst&255)<<24 ----
__global__ __launch_bounds__(256) void bin_k(const int* __restrict__ src_s,
                                             const int* __restrict__ dst_s,
                                             const int* __restrict__ src_t,
                                             const int* __restrict__ dst_t,
                                             int* __restrict__ cursor,
                                             unsigned* __restrict__ pairs, int E) {
    int d = blockIdx.y;
    const int* src = d ? src_t : src_s;
    const int* dst = d ? dst_t : dst_s;
    int* cur = cursor + d * NB;
    __shared__ int h[NB];
    __shared__ int gb[NB];
    int t0 = blockIdx.x * 2048;
    if (t0 >= E) return;
    for (int i = threadIdx.x; i < NB; i += 256) h[i] = 0;
    __syncthreads();
    int rank[8]; unsigned pk[8]; short bk[8];
    #pragma unroll
    for (int j = 0; j < 8; ++j) {
        int e = t0 + j * 256 + threadIdx.x;
        if (e < E) {
            int dd = dst[e], s = src[e];
            bk[j] = (short)(dd >> 8);
            pk[j] = (unsigned)s | ((unsigned)(dd & 255) << 24);
            rank[j] = atomicAdd(&h[dd >> 8], 1);
        } else bk[j] = -1;
    }
    __syncthreads();
    for (int i = threadIdx.x; i < NB; i += 256)
        gb[i] = h[i] ? atomicAdd(&cur[i], h[i]) : 0;
    __syncthreads();
    #pragma unroll
    for (int j = 0; j < 8; ++j)
        if (bk[j] >= 0) pairs[gb[bk[j]] + rank[j]] = pk[j];
}

// ---- per-bucket: LDS node hist -> nspan/dinv, scatter into pad16 CSR ----
// bucket g's CSR region: cbase = align16(bbase[g]) + g*BSLACK
__global__ __launch_bounds__(256) void csrb_k(const unsigned* __restrict__ pairs,
                                              const int* __restrict__ bbase,
                                              int2* __restrict__ nspan,
                                              float* __restrict__ dinv,
                                              int* __restrict__ csr, int N) {
    int d = blockIdx.y, bx = blockIdx.x, t = threadIdx.x;
    int g = d * NB + bx;
    int e0 = bbase[g], e1 = bbase[g + 1];
    int cbase = ((e0 + 15) & ~15) + g * BSLACK;
    float* dv = dinv + (size_t)d * (N + 1);
    int2* ns = nspan + (size_t)d * N;
    __shared__ int lh[256];
    __shared__ int lex[256];
    __shared__ int lc[256];
    lh[t] = 0; lc[t] = 0;
    __syncthreads();
    for (int e = e0 + t; e < e1; e += 256)
        atomicAdd(&lh[pairs[e] >> 24], 1);
    __syncthreads();
    int node = (bx << 8) + t;
    bool valid = node < N;
    int deg = lh[t];
    int pdeg = valid ? (((deg + 16) >> 4) << 4) : 0;   // pad16(deg + self)
    lex[t] = pdeg;
    __syncthreads();
    for (int o = 1; o < 256; o <<= 1) {
        int x = (t >= o) ? lex[t - o] : 0;
        __syncthreads();
        lex[t] += x;
        __syncthreads();
    }
    int start = cbase + lex[t] - pdeg;
    if (valid) {
        ns[node] = make_int2(start, start + pdeg);
        dv[node] = rsqrtf((float)(deg + 1));
    }
    lex[t] = start;               // own-slot overwrite; cross-thread reads after barrier
    __syncthreads();
    for (int e = e0 + t; e < e1; e += 256) {
        unsigned p = pairs[e];
        int dn = p >> 24;
        int rank = atomicAdd(&lc[dn], 1);
        csr[lex[dn] + rank] = (int)(p & 0xffffffu);
    }
    __syncthreads();
    if (valid) {
        int b = lex[t];
        csr[b + deg] = node;                            // self (pre-scaled row IS the self term)
        for (int k = deg + 1; k < pdeg; ++k) csr[b + k] = N;   // sentinel zero-row
    }
    if (bx == 0 && t == 0) dv[N] = 0.f;                 // sentinel row scale
}

// ================= MFMA GEMM =================
__global__ __launch_bounds__(256) void packW_k(const float* __restrict__ W1,
                                               const float* __restrict__ W2,
                                               unsigned short* __restrict__ wp1,
                                               unsigned short* __restrict__ wp2) {
    const float* W = blockIdx.x ? W2 : W1;
    unsigned short* wp = blockIdx.x ? wp2 : wp1;
    for (int idx = threadIdx.x; idx < 2048; idx += 256) {
        int f = idx >> 6, lane = idx & 63;
        int t = f >> 2, c = f & 3;
        int q = lane >> 4, nn = lane & 15;
        #pragma unroll
        for (int j = 0; j < 8; ++j) {
            unsigned u = __float_as_uint(W[(c * 32 + q * 8 + j) * 128 + t * 16 + nn]);
            u += 0x7fffu + ((u >> 16) & 1u);
            wp[idx * 8 + j] = (unsigned short)(u >> 16);
        }
    }
}

// hbuf8 row r (fp8) = fp8( dinv[r] * (x[r] @ W) )  -- pre-scaled; row N = zeros (dinv=0)
__global__ __launch_bounds__(256) void gemm_mfma(const void* __restrict__ xs,
                                                 const void* __restrict__ xt,
                                                 const unsigned short* __restrict__ wp,
                                                 unsigned* __restrict__ hb,
                                                 const float* __restrict__ dinv,
                                                 int N, int in_bf16) {
    int d = blockIdx.y;
    const void* xin = d ? xt : xs;
    unsigned* out = hb + (size_t)d * (N + 1) * 32;
    const float* dv = dinv + (size_t)d * (N + 1);
    __shared__ float cs[64 * 132];
    int tid = threadIdx.x;
    int wave = tid >> 6, lane = tid & 63;
    int quad = lane >> 4, nn = lane & 15;
    long long blockbase = (long long)blockIdx.x * 64;
    long long ar = blockbase + wave * 16 + nn;
    if (ar > N - 1) ar = N - 1;          // inputs have N rows

    bf16x8 a[4];
    if (in_bf16) {
        const uint4* xr = (const uint4*)((const unsigned short*)xin + ar * 128);
        #pragma unroll
        for (int c = 0; c < 4; ++c) {
            union { uint4 u; bf16x8 v; } cv;
            cv.u = xr[c * 4 + quad];
            a[c] = cv.v;
        }
    } else {
        const float4* xr = (const float4*)((const float*)xin + ar * 128);
        #pragma unroll
        for (int c = 0; c < 4; ++c) {
            float4 lo = xr[c * 8 + quad * 2];
            float4 hi = xr[c * 8 + quad * 2 + 1];
            union { bf16x8 v; unsigned u[4]; } au;
            au.u[0] = pack_bf16x2(lo.x, lo.y);
            au.u[1] = pack_bf16x2(lo.z, lo.w);
            au.u[2] = pack_bf16x2(hi.x, hi.y);
            au.u[3] = pack_bf16x2(hi.z, hi.w);
            a[c] = au.v;
        }
    }

    f32x4 acc[8];
    #pragma unroll
    for (int t = 0; t < 8; ++t) acc[t] = (f32x4){0.f, 0.f, 0.f, 0.f};
    const bf16x8* wf = (const bf16x8*)wp;
    #pragma unroll
    for (int t = 0; t < 8; ++t) {
        #pragma unroll
        for (int c = 0; c < 4; ++c) {
            bf16x8 b = wf[(t * 4 + c) * 64 + lane];
            acc[t] = __builtin_amdgcn_mfma_f32_16x16x32_bf16(a[c], b, acc[t], 0, 0, 0);
        }
    }

    #pragma unroll
    for (int t = 0; t < 8; ++t) {
        #pragma unroll
        for (int r = 0; r < 4; ++r)
            cs[(wave * 16 + quad * 4 + r) * 132 + t * 16 + nn] = acc[t][r];
    }
    __syncthreads();

    #pragma unroll
    for (int i = 0; i < 8; ++i) {
        int idx = tid + i * 256;
        int r = idx >> 5, c4 = idx & 31;
        long long row = blockbase + r;
        if (row <= N) {
            float s = dv[row];
            const float4 v = *(const float4*)&cs[r * 132 + c4 * 4];
            int pk = __builtin_amdgcn_cvt_pk_fp8_f32(v.x * s, v.y * s, 0, false);
            pk = __builtin_amdgcn_cvt_pk_fp8_f32(v.z * s, v.w * s, pk, true);
            out[row * 32 + c4] = (unsigned)pk;
        }
    }
}

// ---- shared agg inner loop: 16 edges/iter, 8 gathers in flight, csr prefetch ----
// half-wave handles 8 edges; lane li owns feature dword li of every edge in its half.
#define AGG_BODY(hs, sp)                                                        \
    float a0 = 0.f, a1 = 0.f, a2 = 0.f, a3 = 0.f;                               \
    {                                                                           \
        int e = sp.x;                                                           \
        const int* cp = csr + 8 * half;                                         \
        int4 c0 = *(const int4*)(cp + e);                                       \
        int4 c1 = *(const int4*)(cp + e + 4);                                   \
        for (;;) {                                                              \
            int4 p0 = c0, p1 = c1;                                              \
            int en = e + 16;                                                    \
            c0 = *(const int4*)(cp + en);      /* prefetch (slack-safe) */      \
            c1 = *(const int4*)(cp + en + 4);                                   \
            unsigned u0 = hs[((unsigned)p0.x << 5) | li];                       \
            unsigned u1 = hs[((unsigned)p0.y << 5) | li];                       \
            unsigned u2 = hs[((unsigned)p0.z << 5) | li];                       \
            unsigned u3 = hs[((unsigned)p0.w << 5) | li];                       \
            unsigned u4 = hs[((unsigned)p1.x << 5) | li];                       \
            unsigned u5 = hs[((unsigned)p1.y << 5) | li];                       \
            unsigned u6 = hs[((unsigned)p1.z << 5) | li];                       \
            unsigned u7 = hs[((unsigned)p1.w << 5) | li];                       \
            f32x2 lo, hi;                                                       \
            lo = __builtin_amdgcn_cvt_pk_f32_fp8((int)u0, false);               \
            hi = __builtin_amdgcn_cvt_pk_f32_fp8((int)u0, true);                \
            a0 += lo[0]; a1 += lo[1]; a2 += hi[0]; a3 += hi[1];                 \
            lo = __builtin_amdgcn_cvt_pk_f32_fp8((int)u1, false);               \
            hi = __builtin_amdgcn_cvt_pk_f32_fp8((int)u1, true);                \
            a0 += lo[0]; a1 += lo[1]; a2 += hi[0]; a3 += hi[1];                 \
            lo = __builtin_amdgcn_cvt_pk_f32_fp8((int)u2, false);               \
            hi = __builtin_amdgcn_cvt_pk_f32_fp8((int)u2, true);                \
            a0 += lo[0]; a1 += lo[1]; a2 += hi[0]; a3 += hi[1];                 \
            lo = __builtin_amdgcn_cvt_pk_f32_fp8((int)u3, false);               \
            hi = __builtin_amdgcn_cvt_pk_f32_fp8((int)u3, true);                \
            a0 += lo[0]; a1 += lo[1]; a2 += hi[0]; a3 += hi[1];                 \
            lo = __builtin_amdgcn_cvt_pk_f32_fp8((int)u4, false);               \
            hi = __builtin_amdgcn_cvt_pk_f32_fp8((int)u4, true);                \
            a0 += lo[0]; a1 += lo[1]; a2 += hi[0]; a3 += hi[1];                 \
            lo = __builtin_amdgcn_cvt_pk_f32_fp8((int)u5, false);               \
            hi = __builtin_amdgcn_cvt_pk_f32_fp8((int)u5, true);                \
            a0 += lo[0]; a1 += lo[1]; a2 += hi[0]; a3 += hi[1];                 \
            lo = __builtin_amdgcn_cvt_pk_f32_fp8((int)u6, false);               \
            hi = __builtin_amdgcn_cvt_pk_f32_fp8((int)u6, true);                \
            a0 += lo[0]; a1 += lo[1]; a2 += hi[0]; a3 += hi[1];                 \
            lo = __builtin_amdgcn_cvt_pk_f32_fp8((int)u7, false);               \
            hi = __builtin_amdgcn_cvt_pk_f32_fp8((int)u7, true);                \
            a0 += lo[0]; a1 += lo[1]; a2 += hi[0]; a3 += hi[1];                 \
            if (en >= sp.y) break;                                              \
            e = en;                                                             \
        }                                                                       \
    }                                                                           \
    a0 += __shfl_xor(a0, 32);                                                   \
    a1 += __shfl_xor(a1, 32);                                                   \
    a2 += __shfl_xor(a2, 32);                                                   \
    a3 += __shfl_xor(a3, 32);

// ---- agg layer 1: sum of pre-scaled fp8 rows over pad16 list; bf16+relu out ----
__global__ __launch_bounds__(256) void agg1_k(const unsigned* __restrict__ hb,
                                              const float* __restrict__ dinv,
                                              const int2* __restrict__ nspan,
                                              const int* __restrict__ csr,
                                              const float* __restrict__ bias,
                                              uint2* __restrict__ abuf, int N) {
    int d = blockIdx.y;
    const unsigned* hs = hb + (size_t)d * (N + 1) * 32;
    const float* dv = dinv + (size_t)d * (N + 1);
    const int2* ns = nspan + (size_t)d * N;
    uint2* out = abuf + (size_t)d * N * 32;
    int wave = threadIdx.x >> 6, lane = threadIdx.x & 63;
    int node = blockIdx.x * 4 + wave;
    if (node >= N) return;
    int half = lane >> 5, li = lane & 31;
    int2 sp = ns[node];
    AGG_BODY(hs, sp)
    if (half == 0) {
        float di = dv[node];
        float4 b4 = ((const float4*)bias)[li];
        float o0 = fmaxf(fmaf(di, a0, b4.x), 0.f);
        float o1 = fmaxf(fmaf(di, a1, b4.y), 0.f);
        float o2 = fmaxf(fmaf(di, a2, b4.z), 0.f);
        float o3 = fmaxf(fmaf(di, a3, b4.w), 0.f);
        out[(size_t)node * 32 + li] = make_uint2(pack_bf16x2(o0, o1), pack_bf16x2(o2, o3));
    }
}

// ---- agg layer 2 fused with per-node loss dots ----
__global__ __launch_bounds__(256) void agg2_k(const unsigned* __restrict__ hb,
                                              const float* __restrict__ dinv,
                                              const int2* __restrict__ nspan,
                                              const int* __restrict__ csr,
                                              const float* __restrict__ bias,
                                              const float* __restrict__ clsW,
                                              const float* __restrict__ duW,
                                              const float* __restrict__ diW,
                                              const int* __restrict__ nus,
                                              const int* __restrict__ nut,
                                              float2* __restrict__ nodeDots, int N) {
    int d = blockIdx.y;
    const unsigned* hs = hb + (size_t)d * (N + 1) * 32;
    const float* dv = dinv + (size_t)d * (N + 1);
    const int2* ns = nspan + (size_t)d * N;
    float2* nd = nodeDots + (size_t)d * N;
    int nu = d ? nut[0] : nus[0];
    int wave = threadIdx.x >> 6, lane = threadIdx.x & 63;
    int node = blockIdx.x * 4 + wave;
    if (node >= N) return;
    int half = lane >> 5, li = lane & 31;
    int2 sp = ns[node];
    AGG_BODY(hs, sp)
    float di = dv[node];
    float4 b4 = ((const float4*)bias)[li];
    float o0 = fmaf(di, a0, b4.x);
    float o1 = fmaf(di, a1, b4.y);
    float o2 = fmaf(di, a2, b4.z);
    float o3 = fmaf(di, a3, b4.w);
    int sel = (node >= nu) ? 1 : 0;
    float4 wA = ((const float4*)clsW)[sel * 32 + li];
    float4 wB = ((const float4*)(sel ? diW : duW))[li];
    float p = o0 * wA.x + o1 * wA.y + o2 * wA.z + o3 * wA.w;
    float q = o0 * wB.x + o1 * wB.y + o2 * wB.z + o3 * wB.w;
    #pragma unroll
    for (int o = 16; o > 0; o >>= 1) {
        p += __shfl_xor(p, o);
        q += __shfl_xor(q, o);
    }
    if (lane == 0) nd[node] = make_float2(p, q);
}

// ---- pair loss ----
__global__ __launch_bounds__(256) void loss_k(const float2* __restrict__ nodeDots,
                                              const int* __restrict__ us, const int* __restrict__ is_,
                                              const int* __restrict__ ls,
                                              const int* __restrict__ ut, const int* __restrict__ it,
                                              const int* __restrict__ lt,
                                              const float* __restrict__ clsb,
                                              const float* __restrict__ dub,
                                              const float* __restrict__ dib,
                                              const int* __restrict__ nus,
                                              const int* __restrict__ nut,
                                              float* __restrict__ accum, int Bn, int N) {
    int d = blockIdx.y;
    const float2* nd = nodeDots + (size_t)d * N;
    const int* users = d ? ut : us;
    const int* items = d ? it : is_;
    const int* labels = d ? lt : ls;
    int nu = d ? nut[0] : nus[0];
    float* acc = accum + 3 * d;
    int k = blockIdx.x * 256 + threadIdx.x;
    float bce = 0.f, cu = 0.f, ci = 0.f;
    if (k < Bn) {
        int u = users[k];
        int t = items[k] + nu;
        float2 ud = nd[u];
        float2 id = nd[t];
        float z = ud.x + id.x + clsb[0];
        float y = (float)labels[k];
        float sp = fmaxf(z, 0.f) + log1pf(expf(-fabsf(z)));
        bce = sp - y * z;
        cu = 1.f / (1.f + expf(-(ud.y + dub[0])));
        ci = 1.f / (1.f + expf(-(id.y + dib[0])));
    }
    #pragma unroll
    for (int o = 32; o > 0; o >>= 1) {
        bce += __shfl_xor(bce, o);
        cu += __shfl_xor(cu, o);
        ci += __shfl_xor(ci, o);
    }
    __shared__ float sh[12];
    int lane = threadIdx.x & 63, wave = threadIdx.x >> 6;
    if (lane == 0) { sh[wave * 3 + 0] = bce; sh[wave * 3 + 1] = cu; sh[wave * 3 + 2] = ci; }
    __syncthreads();
    if (threadIdx.x < 3) {
        float v = sh[threadIdx.x] + sh[3 + threadIdx.x] + sh[6 + threadIdx.x] + sh[9 + threadIdx.x];
        atomicAdd(&acc[threadIdx.x], v);
    }
}

__global__ void finalize_k(const float* __restrict__ accum, float* __restrict__ out, float invB) {
    if (threadIdx.x == 0 && blockIdx.x == 0) {
        float clf = (accum[0] + accum[3]) * invB;
        float dom = fabsf((accum[1] - accum[4]) * invB) + fabsf((accum[2] - accum[5]) * invB);
        out[0] = clf + dom;
    }
}

extern "C" void kernel_launch(void* const* d_in, const int* in_sizes, int n_in,
                              void* d_out, int out_size, void* d_ws, size_t ws_size,
                              hipStream_t stream) {
    const float* feats_s = (const float*)d_in[0];
    const float* feats_t = (const float*)d_in[1];
    const float* W1   = (const float*)d_in[2];
    const float* b1   = (const float*)d_in[3];
    const float* W2   = (const float*)d_in[4];
    const float* b2   = (const float*)d_in[5];
    const float* clsW = (const float*)d_in[6];
    const float* clsb = (const float*)d_in[7];
    const float* duW  = (const float*)d_in[8];
    const float* dub  = (const float*)d_in[9];
    const float* diW  = (const float*)d_in[10];
    const float* dib  = (const float*)d_in[11];

    int N = in_sizes[0] / D;
    int E = in_sizes[12];
    int B = in_sizes[16];
    int nb = (N + 255) >> 8;          // real buckets per domain (<= NB)

    char* ws = (char*)d_ws;
    size_t off = 0;
    auto alloc = [&](size_t bytes) -> void* {
        void* p = ws + off;
        off += (bytes + 255) & ~(size_t)255;
        return p;
    };
    int*      bcnt   = (int*)  alloc(2 * NB * 4);
    int*      bbase  = (int*)  alloc((2 * NB + 1) * 4);
    int*      cursor = (int*)  alloc(2 * NB * 4);
    float*    dinv   = (float*)alloc((size_t)2 * (N + 1) * 4);
    int2*     nspan  = (int2*) alloc((size_t)2 * N * 8);
    unsigned* pairs  = (unsigned*)alloc((size_t)2 * E * 4);
    int*      csr    = (int*)  alloc(((size_t)2 * E + 2 * NB * BSLACK + 256) * 4);
    unsigned* hbuf8  = (unsigned*)alloc((size_t)2 * (N + 1) * 128);   // fp8 pre-scaled rows
    unsigned* abuf   = (unsigned*)alloc((size_t)2 * N * 256);         // bf16 agg1 rows
    float2*   nodeDots = (float2*)alloc((size_t)2 * N * 8);
    unsigned short* wp1 = (unsigned short*)alloc(16384 * 2);
    unsigned short* wp2 = (unsigned short*)alloc(16384 * 2);
    float*    accum  = (float*)alloc(128);

    hipMemsetAsync(accum, 0, 6 * sizeof(float), stream);
    hipMemsetAsync(bcnt, 0, 2 * NB * 4, stream);

    const int* esrc_s = (const int*)d_in[12];
    const int* edst_s = (const int*)d_in[13];
    const int* esrc_t = (const int*)d_in[14];
    const int* edst_t = (const int*)d_in[15];
    const int* user_s = (const int*)d_in[16];
    const int* item_s = (const int*)d_in[17];
    const int* lab_s  = (const int*)d_in[18];
    const int* user_t = (const int*)d_in[19];
    const int* item_t = (const int*)d_in[20];
    const int* lab_t  = (const int*)d_in[21];
    const int* nup_s  = (const int*)d_in[22];
    const int* nup_t  = (const int*)d_in[23];

    packW_k<<<2, 256, 0, stream>>>(W1, W2, wp1, wp2);

    bh_k<<<dim3(512, 2), 256, 0, stream>>>(edst_s, edst_t, bcnt, E);
    scanB_k<<<1, 1024, 0, stream>>>(bcnt, bbase, cursor);
    bin_k<<<dim3((E + 2047) / 2048, 2), 256, 0, stream>>>(esrc_s, edst_s, esrc_t, edst_t,
                                                          cursor, pairs, E);
    csrb_k<<<dim3(nb, 2), 256, 0, stream>>>(pairs, bbase, nspan, dinv, csr, N);

    int ngb = (N + 64) / 64;   // covers rows 0..N (incl. sentinel row N)
    gemm_mfma<<<dim3(ngb, 2), 256, 0, stream>>>(feats_s, feats_t, wp1, hbuf8, dinv, N, 0);
    agg1_k<<<dim3((N + 3) / 4, 2), 256, 0, stream>>>(hbuf8, dinv, nspan, csr, b1,
                                                     (uint2*)abuf, N);
    gemm_mfma<<<dim3(ngb, 2), 256, 0, stream>>>(abuf, abuf + (size_t)N * 64, wp2,
                                                hbuf8, dinv, N, 1);
    agg2_k<<<dim3((N + 3) / 4, 2), 256, 0, stream>>>(hbuf8, dinv, nspan, csr, b2,
                                                     clsW, duW, diW, nup_s, nup_t,
                                                     nodeDots, N);
    loss_k<<<dim3((B + 255) / 256, 2), 256, 0, stream>>>(nodeDots,
                                                         user_s, item_s, lab_s,
                                                         user_t, item_t, lab_t,
                                                         clsb, dub, dib, nup_s, nup_t,
                                                         accum, B, N);
    finalize_k<<<1, 64, 0, stream>>>(accum, (float*)d_out, 1.0f / (float)B);
}